// Round 1
// baseline (229.124 us; speedup 1.0000x reference)
//
#include <hip/hip_runtime.h>
#include <hip/hip_bf16.h>

typedef unsigned short ushort_t;
typedef unsigned int uint_t;
typedef __attribute__((ext_vector_type(8))) short short8;
typedef __attribute__((ext_vector_type(4))) float f32x4;

#define S_LEN 1024
#define B_SZ 64
#define H_SZ 512
#define NEG_VAL -1e10f

__device__ __forceinline__ ushort_t f2bf(float x) {
    uint_t u = __float_as_uint(x);
    uint_t r = (u + 0x7fffu + ((u >> 16) & 1u)) >> 16;
    return (ushort_t)r;
}

__device__ __forceinline__ float tanh_fast(float x) {
    // tanh(x) = 1 - 2/(exp(2x)+1); saturates correctly at +-inf
    float e = __expf(2.0f * x);
    return 1.0f - 2.0f / (e + 1.0f);
}

// Convert attn_w[:, 512:1024] (f32, row-major [512][1024]) -> w2 bf16 [512][512]
__global__ void w2conv_kernel(const float* __restrict__ attn_w, ushort_t* __restrict__ w2) {
    int gid = blockIdx.x * 256 + threadIdx.x;  // 65536 quads
    int h = gid >> 7, q = gid & 127;
    float4 v = *(const float4*)(attn_w + (size_t)h * 1024 + 512 + q * 4);
    uint2 p;
    p.x = (uint_t)f2bf(v.x) | ((uint_t)f2bf(v.y) << 16);
    p.y = (uint_t)f2bf(v.z) | ((uint_t)f2bf(v.w) << 16);
    *(uint2*)(w2 + h * 512 + q * 4) = p;
}

// hb[b][h] = attn_b[h] + sum_k hidden[b,k] * attn_w[h,k]   (fp32 exact)
__global__ void hproj_kernel(const float* __restrict__ hidden,
                             const float* __restrict__ attn_w,
                             const float* __restrict__ attn_b,
                             float* __restrict__ hb) {
    int gid = blockIdx.x * 256 + threadIdx.x;  // 32768
    int b = gid >> 9, h = gid & 511;
    const float4* hp = (const float4*)(hidden + (size_t)b * 512);
    const float4* wp = (const float4*)(attn_w + (size_t)h * 1024);
    float a0 = 0.f, a1 = 0.f, a2 = 0.f, a3 = 0.f;
    #pragma unroll 4
    for (int i = 0; i < 128; i += 4) {
        float4 x0 = hp[i + 0], w0 = wp[i + 0];
        a0 += x0.x * w0.x + x0.y * w0.y + x0.z * w0.z + x0.w * w0.w;
        float4 x1 = hp[i + 1], w1 = wp[i + 1];
        a1 += x1.x * w1.x + x1.y * w1.y + x1.z * w1.z + x1.w * w1.w;
        float4 x2 = hp[i + 2], w2v = wp[i + 2];
        a2 += x2.x * w2v.x + x2.y * w2v.y + x2.z * w2v.z + x2.w * w2v.w;
        float4 x3 = hp[i + 3], w3 = wp[i + 3];
        a3 += x3.x * w3.x + x3.y * w3.y + x3.z * w3.z + x3.w * w3.w;
    }
    hb[gid] = attn_b[h] + ((a0 + a1) + (a2 + a3));
}

// Main fused GEMM: per block (one s), compute pre[64 b][512 h] via MFMA,
// epilogue: tanh(pre + hb) * v, reduce over h -> logits[s*64 + b]
__global__ __launch_bounds__(512, 1) void enc_gemm_kernel(
    const float* __restrict__ enc,      // [S,B,H] f32, row (s*64+b) contiguous in h
    const ushort_t* __restrict__ w2,    // [512][512] bf16
    const float* __restrict__ hb,       // [64][512] f32
    const float* __restrict__ vw,       // [512] f32
    float* __restrict__ logits)         // [S][B] f32
{
    __shared__ ushort_t As[2][64 * 32];
    __shared__ ushort_t Bs[2][512 * 32];
    __shared__ float red[8][64];

    const int tid = threadIdx.x;
    const int blk = blockIdx.x;          // = s
    const int w = tid >> 6, l = tid & 63;
    const int lr = l & 15, lq = l >> 4;

    // ---- A staging: thread loads one float4 (row arow, k = akq*4..akq*4+3) ----
    const int arow = tid >> 3, akq = tid & 7;
    const float* aSrc = enc + (size_t)blk * 32768 + arow * 512 + akq * 4;
    const int aLds = arow * 64 + ((((akq >> 1) ^ ((arow >> 1) & 3)) << 4) | ((akq & 1) << 3));

    // ---- B staging: 4 chunks of 8 bf16 per thread ----
    int bGlob[4], bLds[4];
    #pragma unroll
    for (int i = 0; i < 4; i++) {
        int c = i * 512 + tid, h = c >> 2, ks = c & 3;
        bGlob[i] = h * 512 + ks * 8;
        bLds[i] = h * 64 + ((ks ^ ((h >> 1) & 3)) << 4);
    }

    // ---- fragment read offsets (XOR slot swizzle, matches staging) ----
    int aoff[4], boff[4];
    #pragma unroll
    for (int mf = 0; mf < 4; mf++) {
        int row = mf * 16 + lr;
        aoff[mf] = row * 64 + ((lq ^ ((row >> 1) & 3)) << 4);
    }
    #pragma unroll
    for (int nf = 0; nf < 4; nf++) {
        int row = w * 64 + nf * 16 + lr;
        boff[nf] = row * 64 + ((lq ^ ((row >> 1) & 3)) << 4);
    }

    float4 aReg;
    uint4 bReg[4];

    // prologue: load + write k-tile 0
    aReg = *(const float4*)(aSrc);
    #pragma unroll
    for (int i = 0; i < 4; i++) bReg[i] = *(const uint4*)(w2 + bGlob[i]);
    {
        uint2 p;
        p.x = (uint_t)f2bf(aReg.x) | ((uint_t)f2bf(aReg.y) << 16);
        p.y = (uint_t)f2bf(aReg.z) | ((uint_t)f2bf(aReg.w) << 16);
        *(uint2*)((char*)(&As[0][0]) + aLds) = p;
        #pragma unroll
        for (int i = 0; i < 4; i++) *(uint4*)((char*)(&Bs[0][0]) + bLds[i]) = bReg[i];
    }
    __syncthreads();

    f32x4 acc[4][4] = {};

    #pragma unroll 2
    for (int kt = 0; kt < 16; ++kt) {
        const int cur = kt & 1;
        if (kt < 15) {
            aReg = *(const float4*)(aSrc + (kt + 1) * 32);
            #pragma unroll
            for (int i = 0; i < 4; i++) bReg[i] = *(const uint4*)(w2 + bGlob[i] + (kt + 1) * 32);
        }
        short8 af[4], bfr[4];
        #pragma unroll
        for (int mf = 0; mf < 4; mf++)
            af[mf] = *(const short8*)((const char*)(&As[cur][0]) + aoff[mf]);
        #pragma unroll
        for (int nf = 0; nf < 4; nf++)
            bfr[nf] = *(const short8*)((const char*)(&Bs[cur][0]) + boff[nf]);
        #pragma unroll
        for (int mf = 0; mf < 4; mf++)
            #pragma unroll
            for (int nf = 0; nf < 4; nf++)
                acc[mf][nf] = __builtin_amdgcn_mfma_f32_16x16x32_bf16(af[mf], bfr[nf], acc[mf][nf], 0, 0, 0);
        if (kt < 15) {
            uint2 p;
            p.x = (uint_t)f2bf(aReg.x) | ((uint_t)f2bf(aReg.y) << 16);
            p.y = (uint_t)f2bf(aReg.z) | ((uint_t)f2bf(aReg.w) << 16);
            *(uint2*)((char*)(&As[cur ^ 1][0]) + aLds) = p;
            #pragma unroll
            for (int i = 0; i < 4; i++) *(uint4*)((char*)(&Bs[cur ^ 1][0]) + bLds[i]) = bReg[i];
        }
        __syncthreads();
    }

    // ---- epilogue: tanh(pre + hb) * v, reduce over h ----
    float vv[4];
    #pragma unroll
    for (int nf = 0; nf < 4; nf++) vv[nf] = vw[w * 64 + nf * 16 + lr];

    #pragma unroll
    for (int mf = 0; mf < 4; mf++) {
        #pragma unroll
        for (int r = 0; r < 4; r++) {
            int mrow = mf * 16 + lq * 4 + r;   // = b
            const float* hbp = hb + mrow * 512 + w * 64 + lr;
            float p = 0.f;
            #pragma unroll
            for (int nf = 0; nf < 4; nf++) {
                float x = acc[mf][nf][r] + hbp[nf * 16];
                p += tanh_fast(x) * vv[nf];
            }
            p += __shfl_xor(p, 1);
            p += __shfl_xor(p, 2);
            p += __shfl_xor(p, 4);
            p += __shfl_xor(p, 8);
            if (lr == 0) red[w][mrow] = p;
        }
    }
    __syncthreads();
    if (tid < 64) {
        float s = 0.f;
        #pragma unroll
        for (int ww = 0; ww < 8; ww++) s += red[ww][tid];
        logits[blk * 64 + tid] = s;
    }
}

// Masked softmax over s for each b. logits layout [s][b], out [b][s].
__global__ void softmax_kernel(const float* __restrict__ logits,
                               const int* __restrict__ mask,
                               float* __restrict__ out) {
    __shared__ float sred[8];
    int b = blockIdx.x;
    int t = threadIdx.x;  // 256
    float vals[4];
    float mx = -INFINITY;
    #pragma unroll
    for (int i = 0; i < 4; i++) {
        int s = t + i * 256;
        float x = logits[s * 64 + b];
        if (mask[b * 1024 + s] == 0) x = NEG_VAL;
        vals[i] = x;
        mx = fmaxf(mx, x);
    }
    #pragma unroll
    for (int o = 32; o; o >>= 1) mx = fmaxf(mx, __shfl_xor(mx, o));
    int w = t >> 6;
    if ((t & 63) == 0) sred[w] = mx;
    __syncthreads();
    mx = fmaxf(fmaxf(sred[0], sred[1]), fmaxf(sred[2], sred[3]));
    float sum = 0.f;
    #pragma unroll
    for (int i = 0; i < 4; i++) {
        vals[i] = __expf(vals[i] - mx);
        sum += vals[i];
    }
    #pragma unroll
    for (int o = 32; o; o >>= 1) sum += __shfl_xor(sum, o);
    if ((t & 63) == 0) sred[4 + w] = sum;
    __syncthreads();
    float tot = (sred[4] + sred[5]) + (sred[6] + sred[7]);
    float inv = 1.0f / tot;
    #pragma unroll
    for (int i = 0; i < 4; i++) out[b * 1024 + t + i * 256] = vals[i] * inv;
}

extern "C" void kernel_launch(void* const* d_in, const int* in_sizes, int n_in,
                              void* d_out, int out_size, void* d_ws, size_t ws_size,
                              hipStream_t stream) {
    const float* hidden = (const float*)d_in[1];
    const float* enc    = (const float*)d_in[2];
    const int*   mask   = (const int*)d_in[3];
    const float* attn_w = (const float*)d_in[9];
    const float* attn_b = (const float*)d_in[10];
    const float* vw     = (const float*)d_in[11];
    float* out = (float*)d_out;

    char* ws = (char*)d_ws;
    ushort_t* w2 = (ushort_t*)ws;                    // 512 KB
    float* hb     = (float*)(ws + 512 * 1024);       // 128 KB
    float* logits = (float*)(ws + 640 * 1024);       // 256 KB

    w2conv_kernel<<<256, 256, 0, stream>>>(attn_w, w2);
    hproj_kernel<<<128, 256, 0, stream>>>(hidden, attn_w, attn_b, hb);
    enc_gemm_kernel<<<1024, 512, 0, stream>>>(enc, w2, hb, vw, logits);
    softmax_kernel<<<64, 256, 0, stream>>>(logits, mask, out);
}

// Round 2
// 120.235 us; speedup vs baseline: 1.9056x; 1.9056x over previous
//
#include <hip/hip_runtime.h>
#include <hip/hip_bf16.h>

typedef unsigned short ushort_t;
typedef unsigned int uint_t;
typedef __attribute__((ext_vector_type(8))) short short8;
typedef __attribute__((ext_vector_type(4))) float f32x4;

#define NEG_VAL -1e10f

__device__ __forceinline__ ushort_t f2bf(float x) {
    uint_t u = __float_as_uint(x);
    uint_t r = (u + 0x7fffu + ((u >> 16) & 1u)) >> 16;
    return (ushort_t)r;
}

__device__ __forceinline__ float tanh_fast(float x) {
    float e = __expf(2.0f * x);
    return 1.0f - 2.0f / (e + 1.0f);
}

// attn_w[:, 512:1024] (f32 [512][1024]) -> w2 bf16 [512][512]
__global__ void w2conv_kernel(const float* __restrict__ attn_w, ushort_t* __restrict__ w2) {
    int gid = blockIdx.x * 256 + threadIdx.x;  // 65536 quads
    int h = gid >> 7, q = gid & 127;
    float4 v = *(const float4*)(attn_w + (size_t)h * 1024 + 512 + q * 4);
    uint2 p;
    p.x = (uint_t)f2bf(v.x) | ((uint_t)f2bf(v.y) << 16);
    p.y = (uint_t)f2bf(v.z) | ((uint_t)f2bf(v.w) << 16);
    *(uint2*)(w2 + h * 512 + q * 4) = p;
}

// hb[b][h] = attn_b[h] + sum_k hidden[b,k] * attn_w[h,k]   (fp32 exact)
__global__ void hproj_kernel(const float* __restrict__ hidden,
                             const float* __restrict__ attn_w,
                             const float* __restrict__ attn_b,
                             float* __restrict__ hb) {
    int gid = blockIdx.x * 256 + threadIdx.x;  // 32768
    int b = gid >> 9, h = gid & 511;
    const float4* hp = (const float4*)(hidden + (size_t)b * 512);
    const float4* wp = (const float4*)(attn_w + (size_t)h * 1024);
    float a0 = 0.f, a1 = 0.f, a2 = 0.f, a3 = 0.f;
    #pragma unroll 4
    for (int i = 0; i < 128; i += 4) {
        float4 x0 = hp[i + 0], w0 = wp[i + 0];
        a0 += x0.x * w0.x + x0.y * w0.y + x0.z * w0.z + x0.w * w0.w;
        float4 x1 = hp[i + 1], w1 = wp[i + 1];
        a1 += x1.x * w1.x + x1.y * w1.y + x1.z * w1.z + x1.w * w1.w;
        float4 x2 = hp[i + 2], w2v = wp[i + 2];
        a2 += x2.x * w2v.x + x2.y * w2v.y + x2.z * w2v.z + x2.w * w2v.w;
        float4 x3 = hp[i + 3], w3 = wp[i + 3];
        a3 += x3.x * w3.x + x3.y * w3.y + x3.z * w3.z + x3.w * w3.w;
    }
    hb[gid] = attn_b[h] + ((a0 + a1) + (a2 + a3));
}

// GEMM: per block a 128(M=s*64+b) x 128(h) tile; epilogue tanh(pre+hb)*v,
// reduce over the block's 128 h -> part[nt*65536 + row]
__global__ __launch_bounds__(256, 3) void gemm_kernel(
    const float* __restrict__ enc,      // [65536][512] f32 (row = s*64+b)
    const ushort_t* __restrict__ w2,    // [512][512] bf16
    const float* __restrict__ hb,       // [64][512] f32
    const float* __restrict__ vw,       // [512] f32
    float* __restrict__ part)           // [4][65536] f32
{
    __shared__ ushort_t As[2][128 * 32];
    __shared__ ushort_t Bs[2][128 * 32];
    __shared__ float red[2][128];

    const int tid = threadIdx.x;
    const int bid = blockIdx.x;
    // keep the 4 nt-blocks of one mt on the same XCD (bid%8 = XCD round-robin)
    const int xcd = bid & 7, j = bid >> 3;
    const int mt = xcd * 64 + (j >> 2), nt = j & 3;
    const size_t m0 = (size_t)mt * 128;
    const int h0 = nt * 128;

    const int w = tid >> 6, l = tid & 63;
    const int wm = w >> 1, wn = w & 1;
    const int lr = l & 15, lq = l >> 4;

    // ---- staging assignment: thread -> (row, k-half) ----
    const int srow = tid >> 1, skq = tid & 1;
    const float* aSrc = enc + (m0 + srow) * 512 + skq * 16;
    const ushort_t* bSrc = w2 + (size_t)(h0 + srow) * 512 + skq * 16;
    const int ssw = (srow >> 1) & 3;
    const int sws0 = srow * 32 + ((((skq * 2) + 0) ^ ssw) << 3);  // ushort idx
    const int sws1 = srow * 32 + ((((skq * 2) + 1) ^ ssw) << 3);

    // ---- fragment read offsets (same XOR swizzle) ----
    int aoff[4], boff[4];
    #pragma unroll
    for (int mf = 0; mf < 4; mf++) {
        int row = wm * 64 + mf * 16 + lr;
        aoff[mf] = row * 32 + ((lq ^ ((row >> 1) & 3)) << 3);
    }
    #pragma unroll
    for (int nf = 0; nf < 4; nf++) {
        int row = wn * 64 + nf * 16 + lr;
        boff[nf] = row * 32 + ((lq ^ ((row >> 1) & 3)) << 3);
    }

    float4 a0, a1, a2, a3;
    uint4 b0, b1;

    // prologue: stage k-tile 0
    a0 = *(const float4*)(aSrc + 0);
    a1 = *(const float4*)(aSrc + 4);
    a2 = *(const float4*)(aSrc + 8);
    a3 = *(const float4*)(aSrc + 12);
    b0 = *(const uint4*)(bSrc + 0);
    b1 = *(const uint4*)(bSrc + 8);
    {
        uint4 pa0, pa1;
        pa0.x = (uint_t)f2bf(a0.x) | ((uint_t)f2bf(a0.y) << 16);
        pa0.y = (uint_t)f2bf(a0.z) | ((uint_t)f2bf(a0.w) << 16);
        pa0.z = (uint_t)f2bf(a1.x) | ((uint_t)f2bf(a1.y) << 16);
        pa0.w = (uint_t)f2bf(a1.z) | ((uint_t)f2bf(a1.w) << 16);
        pa1.x = (uint_t)f2bf(a2.x) | ((uint_t)f2bf(a2.y) << 16);
        pa1.y = (uint_t)f2bf(a2.z) | ((uint_t)f2bf(a2.w) << 16);
        pa1.z = (uint_t)f2bf(a3.x) | ((uint_t)f2bf(a3.y) << 16);
        pa1.w = (uint_t)f2bf(a3.z) | ((uint_t)f2bf(a3.w) << 16);
        *(uint4*)(&As[0][sws0]) = pa0;
        *(uint4*)(&As[0][sws1]) = pa1;
        *(uint4*)(&Bs[0][sws0]) = b0;
        *(uint4*)(&Bs[0][sws1]) = b1;
    }
    __syncthreads();

    f32x4 acc[4][4] = {};

    #pragma unroll 2
    for (int kt = 0; kt < 16; ++kt) {
        const int cur = kt & 1;
        if (kt < 15) {
            const float* ap = aSrc + (kt + 1) * 32;
            a0 = *(const float4*)(ap + 0);
            a1 = *(const float4*)(ap + 4);
            a2 = *(const float4*)(ap + 8);
            a3 = *(const float4*)(ap + 12);
            const ushort_t* bp = bSrc + (kt + 1) * 32;
            b0 = *(const uint4*)(bp + 0);
            b1 = *(const uint4*)(bp + 8);
        }
        short8 af[4], bfr[4];
        #pragma unroll
        for (int mf = 0; mf < 4; mf++)
            af[mf] = *(const short8*)(&As[cur][aoff[mf]]);
        #pragma unroll
        for (int nf = 0; nf < 4; nf++)
            bfr[nf] = *(const short8*)(&Bs[cur][boff[nf]]);
        #pragma unroll
        for (int mf = 0; mf < 4; mf++)
            #pragma unroll
            for (int nf = 0; nf < 4; nf++)
                acc[mf][nf] = __builtin_amdgcn_mfma_f32_16x16x32_bf16(af[mf], bfr[nf], acc[mf][nf], 0, 0, 0);
        if (kt < 15) {
            uint4 pa0, pa1;
            pa0.x = (uint_t)f2bf(a0.x) | ((uint_t)f2bf(a0.y) << 16);
            pa0.y = (uint_t)f2bf(a0.z) | ((uint_t)f2bf(a0.w) << 16);
            pa0.z = (uint_t)f2bf(a1.x) | ((uint_t)f2bf(a1.y) << 16);
            pa0.w = (uint_t)f2bf(a1.z) | ((uint_t)f2bf(a1.w) << 16);
            pa1.x = (uint_t)f2bf(a2.x) | ((uint_t)f2bf(a2.y) << 16);
            pa1.y = (uint_t)f2bf(a2.z) | ((uint_t)f2bf(a2.w) << 16);
            pa1.z = (uint_t)f2bf(a3.x) | ((uint_t)f2bf(a3.y) << 16);
            pa1.w = (uint_t)f2bf(a3.z) | ((uint_t)f2bf(a3.w) << 16);
            *(uint4*)(&As[cur ^ 1][sws0]) = pa0;
            *(uint4*)(&As[cur ^ 1][sws1]) = pa1;
            *(uint4*)(&Bs[cur ^ 1][sws0]) = b0;
            *(uint4*)(&Bs[cur ^ 1][sws1]) = b1;
        }
        __syncthreads();
    }

    // ---- epilogue: tanh(pre + hb) * v, reduce over this block's 128 h ----
    float vv[4];
    #pragma unroll
    for (int nf = 0; nf < 4; nf++) vv[nf] = vw[h0 + wn * 64 + nf * 16 + lr];

    #pragma unroll
    for (int mf = 0; mf < 4; mf++) {
        #pragma unroll
        for (int r = 0; r < 4; r++) {
            int b = mf * 16 + lq * 4 + r;            // row & 63
            const float* hbp = hb + b * 512 + h0 + wn * 64 + lr;
            float p = 0.f;
            #pragma unroll
            for (int nf = 0; nf < 4; nf++) {
                float x = acc[mf][nf][r] + hbp[nf * 16];
                p += tanh_fast(x) * vv[nf];
            }
            p += __shfl_xor(p, 1);
            p += __shfl_xor(p, 2);
            p += __shfl_xor(p, 4);
            p += __shfl_xor(p, 8);
            if (lr == 0) red[wn][wm * 64 + mf * 16 + lq * 4 + r] = p;
        }
    }
    __syncthreads();
    if (tid < 128) {
        part[(size_t)nt * 65536 + m0 + tid] = red[0][tid] + red[1][tid];
    }
}

// Masked softmax over s for each b. part layout [4][s*64+b], out [b][s].
__global__ void softmax_kernel(const float* __restrict__ part,
                               const int* __restrict__ mask,
                               float* __restrict__ out) {
    __shared__ float sred[8];
    int b = blockIdx.x;
    int t = threadIdx.x;  // 256
    float vals[4];
    float mx = -INFINITY;
    #pragma unroll
    for (int i = 0; i < 4; i++) {
        int s = t + i * 256;
        int row = s * 64 + b;
        float x = part[row] + part[65536 + row] + part[131072 + row] + part[196608 + row];
        if (mask[b * 1024 + s] == 0) x = NEG_VAL;
        vals[i] = x;
        mx = fmaxf(mx, x);
    }
    #pragma unroll
    for (int o = 32; o; o >>= 1) mx = fmaxf(mx, __shfl_xor(mx, o));
    int w = t >> 6;
    if ((t & 63) == 0) sred[w] = mx;
    __syncthreads();
    mx = fmaxf(fmaxf(sred[0], sred[1]), fmaxf(sred[2], sred[3]));
    float sum = 0.f;
    #pragma unroll
    for (int i = 0; i < 4; i++) {
        vals[i] = __expf(vals[i] - mx);
        sum += vals[i];
    }
    #pragma unroll
    for (int o = 32; o; o >>= 1) sum += __shfl_xor(sum, o);
    if ((t & 63) == 0) sred[4 + w] = sum;
    __syncthreads();
    float tot = (sred[4] + sred[5]) + (sred[6] + sred[7]);
    float inv = 1.0f / tot;
    #pragma unroll
    for (int i = 0; i < 4; i++) out[b * 1024 + t + i * 256] = vals[i] * inv;
}

extern "C" void kernel_launch(void* const* d_in, const int* in_sizes, int n_in,
                              void* d_out, int out_size, void* d_ws, size_t ws_size,
                              hipStream_t stream) {
    const float* hidden = (const float*)d_in[1];
    const float* enc    = (const float*)d_in[2];
    const int*   mask   = (const int*)d_in[3];
    const float* attn_w = (const float*)d_in[9];
    const float* attn_b = (const float*)d_in[10];
    const float* vw     = (const float*)d_in[11];
    float* out = (float*)d_out;

    char* ws = (char*)d_ws;
    ushort_t* w2 = (ushort_t*)ws;                    // 512 KB
    float* hb   = (float*)(ws + 512 * 1024);         // 128 KB
    float* part = (float*)(ws + 640 * 1024);         // 1 MB (4 x 65536 f32)

    w2conv_kernel<<<256, 256, 0, stream>>>(attn_w, w2);
    hproj_kernel<<<128, 256, 0, stream>>>(hidden, attn_w, attn_b, hb);
    gemm_kernel<<<2048, 256, 0, stream>>>(enc, w2, hb, vw, part);
    softmax_kernel<<<64, 256, 0, stream>>>(part, mask, out);
}

// Round 4
// 118.289 us; speedup vs baseline: 1.9370x; 1.0164x over previous
//
#include <hip/hip_runtime.h>
#include <hip/hip_bf16.h>

typedef unsigned short ushort_t;
typedef unsigned int uint_t;
typedef __attribute__((ext_vector_type(8))) short short8;
typedef __attribute__((ext_vector_type(4))) float f32x4;

#define NEG_VAL -1e10f

#define GL16(gp, lp) __builtin_amdgcn_global_load_lds( \
    (const __attribute__((address_space(1))) uint_t*)(gp), \
    (__attribute__((address_space(3))) uint_t*)(lp), 16, 0, 0)

__device__ __forceinline__ ushort_t f2bf(float x) {
    uint_t u = __float_as_uint(x);
    uint_t r = (u + 0x7fffu + ((u >> 16) & 1u)) >> 16;
    return (ushort_t)r;
}

__device__ __forceinline__ uint_t pkbf(float a, float b) {
    return (uint_t)f2bf(a) | ((uint_t)f2bf(b) << 16);
}

__device__ __forceinline__ float tanh_fast(float x) {
    float e = __expf(2.0f * x);
    return 1.0f - 2.0f / (e + 1.0f);
}

// attn_w[:, 512:1024] (f32 [512][1024]) -> w2 bf16 [512][512]
__global__ void w2conv_kernel(const float* __restrict__ attn_w, ushort_t* __restrict__ w2) {
    int gid = blockIdx.x * 256 + threadIdx.x;  // 65536 quads
    int h = gid >> 7, q = gid & 127;
    float4 v = *(const float4*)(attn_w + (size_t)h * 1024 + 512 + q * 4);
    uint2 p;
    p.x = pkbf(v.x, v.y);
    p.y = pkbf(v.z, v.w);
    *(uint2*)(w2 + h * 512 + q * 4) = p;
}

// hb[b][h] = attn_b[h] + sum_k hidden[b,k] * attn_w[h,k]   (fp32 exact)
__global__ void hproj_kernel(const float* __restrict__ hidden,
                             const float* __restrict__ attn_w,
                             const float* __restrict__ attn_b,
                             float* __restrict__ hb) {
    int gid = blockIdx.x * 256 + threadIdx.x;  // 32768
    int b = gid >> 9, h = gid & 511;
    const float4* hp = (const float4*)(hidden + (size_t)b * 512);
    const float4* wp = (const float4*)(attn_w + (size_t)h * 1024);
    float a0 = 0.f, a1 = 0.f, a2 = 0.f, a3 = 0.f;
    #pragma unroll 4
    for (int i = 0; i < 128; i += 4) {
        float4 x0 = hp[i + 0], w0 = wp[i + 0];
        a0 += x0.x * w0.x + x0.y * w0.y + x0.z * w0.z + x0.w * w0.w;
        float4 x1 = hp[i + 1], w1 = wp[i + 1];
        a1 += x1.x * w1.x + x1.y * w1.y + x1.z * w1.z + x1.w * w1.w;
        float4 x2 = hp[i + 2], w2v = wp[i + 2];
        a2 += x2.x * w2v.x + x2.y * w2v.y + x2.z * w2v.z + x2.w * w2v.w;
        float4 x3 = hp[i + 3], w3 = wp[i + 3];
        a3 += x3.x * w3.x + x3.y * w3.y + x3.z * w3.z + x3.w * w3.w;
    }
    hb[gid] = attn_b[h] + ((a0 + a1) + (a2 + a3));
}

// GEMM: 128(M) x 128(N=h) tile per block, BK=32, global_load_lds staging.
// A kept fp32 in LDS; converted to bf16 on the LDS->reg read path.
// Epilogue: tanh(pre + hb) * v, reduce over the block's 128 h.
__global__ __launch_bounds__(256, 3) void gemm_kernel(
    const float* __restrict__ enc,      // [65536][512] f32 (row = s*64+b)
    const ushort_t* __restrict__ w2,    // [512][512] bf16
    const float* __restrict__ hb,       // [64][512] f32
    const float* __restrict__ vw,       // [512] f32
    float* __restrict__ part)           // [4][65536] f32
{
    __shared__ __align__(16) float As[2][128 * 32];      // 16 KB x2, fp32
    __shared__ __align__(16) ushort_t Bs[2][128 * 32];   // 8 KB x2, bf16
    __shared__ float red[2][128];

    const int tid = threadIdx.x;
    const int bid = blockIdx.x;
    // keep the 4 nt-blocks of one mt on the same XCD (bid%8 = XCD round-robin)
    const int xcd = bid & 7, j = bid >> 3;
    const int mt = xcd * 64 + (j >> 2), nt = j & 3;
    const size_t m0 = (size_t)mt * 128;
    const int h0 = nt * 128;

    const int wv = tid >> 6, l = tid & 63;
    const int wm = wv >> 1, wn = wv & 1;
    const int lr = l & 15, lq = l >> 4;

    // ---- A staging: 4 gload_lds issues/thread; chunk c = wv*4+i covers rows 8c..8c+7
    // lane l -> row' = c*8 + (l>>3), 16B-unit p = l&7; pre-swizzled source j = p ^ (row'&7)
    const float* aG[4];
    int aLc[4];  // LDS float index of chunk base
    #pragma unroll
    for (int i = 0; i < 4; i++) {
        int c = wv * 4 + i;
        int rowA = c * 8 + (l >> 3);
        int jA = (l & 7) ^ (l >> 3);           // rowA&7 == l>>3
        aG[i] = enc + (m0 + rowA) * 512 + jA * 4;
        aLc[i] = c * 256;
    }
    // ---- B staging: 2 issues/thread; chunk c = wv*2+i covers rows 16c..16c+15
    // lane l -> row'' = c*16 + (l>>2), unit p = l&3; source j = p ^ ((row''>>1)&3)
    const ushort_t* bG[2];
    int bLc[2];  // LDS ushort index of chunk base
    #pragma unroll
    for (int i = 0; i < 2; i++) {
        int c = wv * 2 + i;
        int rowB = c * 16 + (l >> 2);
        int jB = (l & 3) ^ ((l >> 3) & 3);     // (rowB>>1)&3 == (l>>3)&3
        bG[i] = w2 + (size_t)(h0 + rowB) * 512 + jB * 8;
        bLc[i] = c * 512;
    }

    // ---- fragment read offsets (inverse of the same XOR involutions) ----
    int aoffL[4], aoffH[4], boff[4];
    #pragma unroll
    for (int mf = 0; mf < 4; mf++) {
        int r = wm * 64 + mf * 16 + lr;
        aoffL[mf] = (r * 8 + ((lq * 2 + 0) ^ (r & 7))) * 4;  // float idx
        aoffH[mf] = (r * 8 + ((lq * 2 + 1) ^ (r & 7))) * 4;
    }
    #pragma unroll
    for (int nf = 0; nf < 4; nf++) {
        int r = wn * 64 + nf * 16 + lr;
        boff[nf] = (r * 4 + (lq ^ ((r >> 1) & 3))) * 8;      // ushort idx
    }

    // prologue: stage k-tile 0
    #pragma unroll
    for (int i = 0; i < 4; i++) GL16(aG[i], &As[0][aLc[i]]);
    #pragma unroll
    for (int i = 0; i < 2; i++) GL16(bG[i], &Bs[0][bLc[i]]);
    __syncthreads();

    f32x4 acc[4][4] = {};

    #pragma unroll 2
    for (int kt = 0; kt < 16; ++kt) {
        const int cur = kt & 1;
        if (kt < 15) {
            #pragma unroll
            for (int i = 0; i < 4; i++) GL16(aG[i] + (kt + 1) * 32, &As[cur ^ 1][aLc[i]]);
            #pragma unroll
            for (int i = 0; i < 2; i++) GL16(bG[i] + (kt + 1) * 32, &Bs[cur ^ 1][bLc[i]]);
        }
        short8 af[4], bfr[4];
        #pragma unroll
        for (int nf = 0; nf < 4; nf++)
            bfr[nf] = *(const short8*)(&Bs[cur][boff[nf]]);
        #pragma unroll
        for (int mf = 0; mf < 4; mf++) {
            f32x4 lo = *(const f32x4*)(&As[cur][aoffL[mf]]);
            f32x4 hi = *(const f32x4*)(&As[cur][aoffH[mf]]);
            union { short8 s; uint_t u[4]; } t;
            t.u[0] = pkbf(lo[0], lo[1]);
            t.u[1] = pkbf(lo[2], lo[3]);
            t.u[2] = pkbf(hi[0], hi[1]);
            t.u[3] = pkbf(hi[2], hi[3]);
            af[mf] = t.s;
        }
        #pragma unroll
        for (int mf = 0; mf < 4; mf++)
            #pragma unroll
            for (int nf = 0; nf < 4; nf++)
                acc[mf][nf] = __builtin_amdgcn_mfma_f32_16x16x32_bf16(af[mf], bfr[nf], acc[mf][nf], 0, 0, 0);
        __syncthreads();
    }

    // ---- epilogue: tanh(pre + hb) * v, reduce over this block's 128 h ----
    float vv[4];
    #pragma unroll
    for (int nf = 0; nf < 4; nf++) vv[nf] = vw[h0 + wn * 64 + nf * 16 + lr];

    #pragma unroll
    for (int mf = 0; mf < 4; mf++) {
        #pragma unroll
        for (int r = 0; r < 4; r++) {
            int b = mf * 16 + lq * 4 + r;            // row & 63
            const float* hbp = hb + b * 512 + h0 + wn * 64 + lr;
            float p = 0.f;
            #pragma unroll
            for (int nf = 0; nf < 4; nf++) {
                float x = acc[mf][nf][r] + hbp[nf * 16];
                p += tanh_fast(x) * vv[nf];
            }
            p += __shfl_xor(p, 1);
            p += __shfl_xor(p, 2);
            p += __shfl_xor(p, 4);
            p += __shfl_xor(p, 8);
            if (lr == 0) red[wn][wm * 64 + mf * 16 + lq * 4 + r] = p;
        }
    }
    __syncthreads();
    if (tid < 128) {
        part[(size_t)nt * 65536 + m0 + tid] = red[0][tid] + red[1][tid];
    }
}

// Masked softmax over s for each b. part layout [4][s*64+b], out [b][s].
__global__ void softmax_kernel(const float* __restrict__ part,
                               const int* __restrict__ mask,
                               float* __restrict__ out) {
    __shared__ float sred[8];
    int b = blockIdx.x;
    int t = threadIdx.x;  // 256
    float vals[4];
    float mx = -INFINITY;
    #pragma unroll
    for (int i = 0; i < 4; i++) {
        int s = t + i * 256;
        int row = s * 64 + b;
        float x = part[row] + part[65536 + row] + part[131072 + row] + part[196608 + row];
        if (mask[b * 1024 + s] == 0) x = NEG_VAL;
        vals[i] = x;
        mx = fmaxf(mx, x);
    }
    #pragma unroll
    for (int o = 32; o; o >>= 1) mx = fmaxf(mx, __shfl_xor(mx, o));
    int w = t >> 6;
    if ((t & 63) == 0) sred[w] = mx;
    __syncthreads();
    mx = fmaxf(fmaxf(sred[0], sred[1]), fmaxf(sred[2], sred[3]));
    float sum = 0.f;
    #pragma unroll
    for (int i = 0; i < 4; i++) {
        vals[i] = __expf(vals[i] - mx);
        sum += vals[i];
    }
    #pragma unroll
    for (int o = 32; o; o >>= 1) sum += __shfl_xor(sum, o);
    if ((t & 63) == 0) sred[4 + w] = sum;
    __syncthreads();
    float tot = (sred[4] + sred[5]) + (sred[6] + sred[7]);
    float inv = 1.0f / tot;
    #pragma unroll
    for (int i = 0; i < 4; i++) out[b * 1024 + t + i * 256] = vals[i] * inv;
}

extern "C" void kernel_launch(void* const* d_in, const int* in_sizes, int n_in,
                              void* d_out, int out_size, void* d_ws, size_t ws_size,
                              hipStream_t stream) {
    const float* hidden = (const float*)d_in[1];
    const float* enc    = (const float*)d_in[2];
    const int*   mask   = (const int*)d_in[3];
    const float* attn_w = (const float*)d_in[9];
    const float* attn_b = (const float*)d_in[10];
    const float* vw     = (const float*)d_in[11];
    float* out = (float*)d_out;

    char* ws = (char*)d_ws;
    ushort_t* w2 = (ushort_t*)ws;                    // 512 KB
    float* hb   = (float*)(ws + 512 * 1024);         // 128 KB
    float* part = (float*)(ws + 640 * 1024);         // 1 MB (4 x 65536 f32)

    w2conv_kernel<<<256, 256, 0, stream>>>(attn_w, w2);
    hproj_kernel<<<128, 256, 0, stream>>>(hidden, attn_w, attn_b, hb);
    gemm_kernel<<<2048, 256, 0, stream>>>(enc, w2, hb, vw, part);
    softmax_kernel<<<64, 256, 0, stream>>>(part, mask, out);
}

// Round 5
// 108.839 us; speedup vs baseline: 2.1052x; 1.0868x over previous
//
#include <hip/hip_runtime.h>
#include <hip/hip_bf16.h>

typedef unsigned short ushort_t;
typedef unsigned int uint_t;
typedef __attribute__((ext_vector_type(8))) short short8;
typedef __attribute__((ext_vector_type(4))) float f32x4;

#define NEG_VAL -1e10f

#define GL16(gp, lp) __builtin_amdgcn_global_load_lds( \
    (const __attribute__((address_space(1))) uint_t*)(gp), \
    (__attribute__((address_space(3))) uint_t*)(lp), 16, 0, 0)

__device__ __forceinline__ ushort_t f2bf(float x) {
    uint_t u = __float_as_uint(x);
    uint_t r = (u + 0x7fffu + ((u >> 16) & 1u)) >> 16;
    return (ushort_t)r;
}

__device__ __forceinline__ uint_t pkbf(float a, float b) {
    return (uint_t)f2bf(a) | ((uint_t)f2bf(b) << 16);
}

__device__ __forceinline__ float tanh_fast(float x) {
    float e = __expf(2.0f * x);
    return 1.0f - 2.0f / (e + 1.0f);
}

// attn_w[:, 512:1024] (f32 [512][1024]) -> w2 bf16 [512][512]
__global__ void w2conv_kernel(const float* __restrict__ attn_w, ushort_t* __restrict__ w2) {
    int gid = blockIdx.x * 256 + threadIdx.x;  // 65536 quads
    int h = gid >> 7, q = gid & 127;
    float4 v = *(const float4*)(attn_w + (size_t)h * 1024 + 512 + q * 4);
    uint2 p;
    p.x = pkbf(v.x, v.y);
    p.y = pkbf(v.z, v.w);
    *(uint2*)(w2 + h * 512 + q * 4) = p;
}

// hb[b][h] = attn_b[h] + sum_k hidden[b,k] * attn_w[h,k]   (fp32 exact)
__global__ void hproj_kernel(const float* __restrict__ hidden,
                             const float* __restrict__ attn_w,
                             const float* __restrict__ attn_b,
                             float* __restrict__ hb) {
    int gid = blockIdx.x * 256 + threadIdx.x;  // 32768
    int b = gid >> 9, h = gid & 511;
    const float4* hp = (const float4*)(hidden + (size_t)b * 512);
    const float4* wp = (const float4*)(attn_w + (size_t)h * 1024);
    float a0 = 0.f, a1 = 0.f, a2 = 0.f, a3 = 0.f;
    #pragma unroll 4
    for (int i = 0; i < 128; i += 4) {
        float4 x0 = hp[i + 0], w0 = wp[i + 0];
        a0 += x0.x * w0.x + x0.y * w0.y + x0.z * w0.z + x0.w * w0.w;
        float4 x1 = hp[i + 1], w1 = wp[i + 1];
        a1 += x1.x * w1.x + x1.y * w1.y + x1.z * w1.z + x1.w * w1.w;
        float4 x2 = hp[i + 2], w2v = wp[i + 2];
        a2 += x2.x * w2v.x + x2.y * w2v.y + x2.z * w2v.z + x2.w * w2v.w;
        float4 x3 = hp[i + 3], w3 = wp[i + 3];
        a3 += x3.x * w3.x + x3.y * w3.y + x3.z * w3.z + x3.w * w3.w;
    }
    hb[gid] = attn_b[h] + ((a0 + a1) + (a2 + a3));
}

// GEMM: 128(M) x 512(full N) per block -> enc read exactly ONCE.
// 8 waves (2M x 4N), BK=32, 3-deep LDS ring, depth-2 prefetch, counted vmcnt.
// Epilogue: tanh(pre + hb) * v, reduce over all 512 h -> logits directly.
__global__ __launch_bounds__(512, 2) void gemm_kernel(
    const float* __restrict__ enc,      // [65536][512] f32 (row = s*64+b)
    const ushort_t* __restrict__ w2,    // [512][512] bf16
    const float* __restrict__ hb,       // [64][512] f32
    const float* __restrict__ vw,       // [512] f32
    float* __restrict__ logits)         // [65536] f32 (= [s][b])
{
    __shared__ __align__(16) float As[3][128 * 32];      // 16 KB x3 fp32
    __shared__ __align__(16) ushort_t Bs[3][512 * 32];   // 32 KB x3 bf16
    __shared__ float red[4][128];

    const int tid = threadIdx.x;
    const int wv = tid >> 6, l = tid & 63;
    const int wm = wv >> 2, wn = wv & 3;
    const int lr = l & 15, lq = l >> 4;
    const size_t m0 = (size_t)blockIdx.x * 128;

    // ---- A staging: 2 gload_lds/thread. instr i covers 16B-units u=512i+64wv+l
    // row = u>>3, slot p = l&7, swizzled source unit j = p ^ (row&7), row&7 = l>>3
    const float* aG[2];
    uint_t aL[2];
    #pragma unroll
    for (int i = 0; i < 2; i++) {
        int u = 512 * i + 64 * wv + l;
        int row = u >> 3;
        int j = (l & 7) ^ (l >> 3);
        aG[i] = enc + (m0 + row) * 512 + j * 4;
        aL[i] = (uint_t)(512 * i + 64 * wv) * 16;  // wave-uniform byte base
    }
    // ---- B staging: 4 gload_lds/thread. units u=512i+64wv+l, row=u>>2, p=l&3
    // source unit j = p ^ ((row>>1)&3), (row>>1)&3 = (l>>3)&3
    const ushort_t* bG[4];
    uint_t bL[4];
    #pragma unroll
    for (int i = 0; i < 4; i++) {
        int u = 512 * i + 64 * wv + l;
        int row = u >> 2;
        int j = (l & 3) ^ ((l >> 3) & 3);
        bG[i] = w2 + (size_t)row * 512 + j * 8;
        bL[i] = (uint_t)(512 * i + 64 * wv) * 16;
    }

    // ---- fragment read byte-offsets (inverse of same involutions) ----
    uint_t aoffL[4], aoffH[4], boff[8];
    #pragma unroll
    for (int mf = 0; mf < 4; mf++) {
        int row = wm * 64 + mf * 16 + lr;
        aoffL[mf] = (uint_t)row * 128 + (uint_t)(((lq * 2 + 0) ^ (row & 7)) * 16);
        aoffH[mf] = (uint_t)row * 128 + (uint_t)(((lq * 2 + 1) ^ (row & 7)) * 16);
    }
    #pragma unroll
    for (int nf = 0; nf < 8; nf++) {
        int r = wn * 128 + nf * 16 + lr;
        boff[nf] = (uint_t)r * 64 + (uint_t)((lq ^ ((r >> 1) & 3)) * 16);
    }

    #define STAGE(kt, buf) do { \
        _Pragma("unroll") \
        for (int i = 0; i < 2; i++) GL16(aG[i] + (kt) * 32, (char*)(&As[(buf)][0]) + aL[i]); \
        _Pragma("unroll") \
        for (int i = 0; i < 4; i++) GL16(bG[i] + (kt) * 32, (char*)(&Bs[(buf)][0]) + bL[i]); \
    } while (0)

    // prologue: depth-2 prefetch
    STAGE(0, 0);
    STAGE(1, 1);
    asm volatile("s_waitcnt vmcnt(6)" ::: "memory");
    __builtin_amdgcn_sched_barrier(0);
    __builtin_amdgcn_s_barrier();

    f32x4 acc[4][8] = {};

    #pragma unroll
    for (int kt = 0; kt < 16; ++kt) {
        const int cur = kt % 3;
        // LDS -> regs (buf[cur] is ready)
        short8 af[4], bfr[8];
        #pragma unroll
        for (int nf = 0; nf < 8; nf++)
            bfr[nf] = *(const short8*)((const char*)(&Bs[cur][0]) + boff[nf]);
        #pragma unroll
        for (int mf = 0; mf < 4; mf++) {
            f32x4 lo = *(const f32x4*)((const char*)(&As[cur][0]) + aoffL[mf]);
            f32x4 hi = *(const f32x4*)((const char*)(&As[cur][0]) + aoffH[mf]);
            union { short8 s; uint_t u[4]; } t;
            t.u[0] = pkbf(lo[0], lo[1]);
            t.u[1] = pkbf(lo[2], lo[3]);
            t.u[2] = pkbf(hi[0], hi[1]);
            t.u[3] = pkbf(hi[2], hi[3]);
            af[mf] = t.s;
        }
        asm volatile("s_waitcnt lgkmcnt(0)" ::: "memory");
        __builtin_amdgcn_sched_barrier(0);
        __builtin_amdgcn_s_barrier();           // all waves done reading buf[cur]
        if (kt + 2 <= 15) {
            const int nb = (kt + 2) % 3;
            STAGE(kt + 2, nb);
        }
        #pragma unroll
        for (int mf = 0; mf < 4; mf++)
            #pragma unroll
            for (int nf = 0; nf < 8; nf++)
                acc[mf][nf] = __builtin_amdgcn_mfma_f32_16x16x32_bf16(af[mf], bfr[nf], acc[mf][nf], 0, 0, 0);
        if (kt < 15) {
            if (kt < 14) { asm volatile("s_waitcnt vmcnt(6)" ::: "memory"); }
            else         { asm volatile("s_waitcnt vmcnt(0)" ::: "memory"); }
            __builtin_amdgcn_sched_barrier(0);
            __builtin_amdgcn_s_barrier();       // buf[kt+1] fully written
        }
    }
    #undef STAGE

    // ---- epilogue: tanh(pre + hb) * v, reduce over all 512 h ----
    float vv[8];
    #pragma unroll
    for (int nf = 0; nf < 8; nf++) vv[nf] = vw[wn * 128 + nf * 16 + lr];

    #pragma unroll
    for (int mf = 0; mf < 4; mf++) {
        #pragma unroll
        for (int r = 0; r < 4; r++) {
            int row = wm * 64 + mf * 16 + lq * 4 + r;   // 0..127
            int b = row & 63;
            const float* hbp = hb + b * 512 + wn * 128 + lr;
            float p = 0.f;
            #pragma unroll
            for (int nf = 0; nf < 8; nf++) {
                float x = acc[mf][nf][r] + hbp[nf * 16];
                p += tanh_fast(x) * vv[nf];
            }
            p += __shfl_xor(p, 1);
            p += __shfl_xor(p, 2);
            p += __shfl_xor(p, 4);
            p += __shfl_xor(p, 8);
            if (lr == 0) red[wn][row] = p;
        }
    }
    __syncthreads();
    if (tid < 128) {
        logits[m0 + tid] = (red[0][tid] + red[1][tid]) + (red[2][tid] + red[3][tid]);
    }
}

// Masked softmax over s for each b. logits layout [s][b], out [b][s].
__global__ void softmax_kernel(const float* __restrict__ logits,
                               const int* __restrict__ mask,
                               float* __restrict__ out) {
    __shared__ float sred[8];
    int b = blockIdx.x;
    int t = threadIdx.x;  // 256
    float vals[4];
    float mx = -INFINITY;
    #pragma unroll
    for (int i = 0; i < 4; i++) {
        int s = t + i * 256;
        float x = logits[s * 64 + b];
        if (mask[b * 1024 + s] == 0) x = NEG_VAL;
        vals[i] = x;
        mx = fmaxf(mx, x);
    }
    #pragma unroll
    for (int o = 32; o; o >>= 1) mx = fmaxf(mx, __shfl_xor(mx, o));
    int w = t >> 6;
    if ((t & 63) == 0) sred[w] = mx;
    __syncthreads();
    mx = fmaxf(fmaxf(sred[0], sred[1]), fmaxf(sred[2], sred[3]));
    float sum = 0.f;
    #pragma unroll
    for (int i = 0; i < 4; i++) {
        vals[i] = __expf(vals[i] - mx);
        sum += vals[i];
    }
    #pragma unroll
    for (int o = 32; o; o >>= 1) sum += __shfl_xor(sum, o);
    if ((t & 63) == 0) sred[4 + w] = sum;
    __syncthreads();
    float tot = (sred[4] + sred[5]) + (sred[6] + sred[7]);
    float inv = 1.0f / tot;
    #pragma unroll
    for (int i = 0; i < 4; i++) out[b * 1024 + t + i * 256] = vals[i] * inv;
}

extern "C" void kernel_launch(void* const* d_in, const int* in_sizes, int n_in,
                              void* d_out, int out_size, void* d_ws, size_t ws_size,
                              hipStream_t stream) {
    const float* hidden = (const float*)d_in[1];
    const float* enc    = (const float*)d_in[2];
    const int*   mask   = (const int*)d_in[3];
    const float* attn_w = (const float*)d_in[9];
    const float* attn_b = (const float*)d_in[10];
    const float* vw     = (const float*)d_in[11];
    float* out = (float*)d_out;

    char* ws = (char*)d_ws;
    ushort_t* w2  = (ushort_t*)ws;                   // 512 KB
    float* hb     = (float*)(ws + 512 * 1024);       // 128 KB
    float* logits = (float*)(ws + 640 * 1024);       // 256 KB

    w2conv_kernel<<<256, 256, 0, stream>>>(attn_w, w2);
    hproj_kernel<<<128, 256, 0, stream>>>(hidden, attn_w, attn_b, hb);
    gemm_kernel<<<512, 512, 0, stream>>>(enc, w2, hb, vw, logits);
    softmax_kernel<<<64, 256, 0, stream>>>(logits, mask, out);
}

// Round 6
// 100.029 us; speedup vs baseline: 2.2906x; 1.0881x over previous
//
#include <hip/hip_runtime.h>
#include <hip/hip_bf16.h>

typedef unsigned short ushort_t;
typedef unsigned int uint_t;
typedef __attribute__((ext_vector_type(8))) short short8;
typedef __attribute__((ext_vector_type(4))) float f32x4;

#define NEG_VAL -1e10f

#define GL16(gp, lp) __builtin_amdgcn_global_load_lds( \
    (const __attribute__((address_space(1))) uint_t*)(gp), \
    (__attribute__((address_space(3))) uint_t*)(lp), 16, 0, 0)

__device__ __forceinline__ ushort_t f2bf(float x) {
    uint_t u = __float_as_uint(x);
    uint_t r = (u + 0x7fffu + ((u >> 16) & 1u)) >> 16;
    return (ushort_t)r;
}

__device__ __forceinline__ uint_t pkbf(float a, float b) {
    return (uint_t)f2bf(a) | ((uint_t)f2bf(b) << 16);
}

__device__ __forceinline__ float tanh_fast(float x) {
    float e = __expf(2.0f * x);
    return 1.0f - 2.0f / (e + 1.0f);
}

// attn_w[:, 512:1024] (f32 [512][1024]) -> w2 bf16 [512][512]
__global__ void w2conv_kernel(const float* __restrict__ attn_w, ushort_t* __restrict__ w2) {
    int gid = blockIdx.x * 256 + threadIdx.x;  // 65536 quads
    int h = gid >> 7, q = gid & 127;
    float4 v = *(const float4*)(attn_w + (size_t)h * 1024 + 512 + q * 4);
    uint2 p;
    p.x = pkbf(v.x, v.y);
    p.y = pkbf(v.z, v.w);
    *(uint2*)(w2 + h * 512 + q * 4) = p;
}

// hb[b][h] = attn_b[h] + sum_k hidden[b,k] * attn_w[h,k]   (fp32 exact)
__global__ void hproj_kernel(const float* __restrict__ hidden,
                             const float* __restrict__ attn_w,
                             const float* __restrict__ attn_b,
                             float* __restrict__ hb) {
    int gid = blockIdx.x * 256 + threadIdx.x;  // 32768
    int b = gid >> 9, h = gid & 511;
    const float4* hp = (const float4*)(hidden + (size_t)b * 512);
    const float4* wp = (const float4*)(attn_w + (size_t)h * 1024);
    float a0 = 0.f, a1 = 0.f, a2 = 0.f, a3 = 0.f;
    #pragma unroll 4
    for (int i = 0; i < 128; i += 4) {
        float4 x0 = hp[i + 0], w0 = wp[i + 0];
        a0 += x0.x * w0.x + x0.y * w0.y + x0.z * w0.z + x0.w * w0.w;
        float4 x1 = hp[i + 1], w1 = wp[i + 1];
        a1 += x1.x * w1.x + x1.y * w1.y + x1.z * w1.z + x1.w * w1.w;
        float4 x2 = hp[i + 2], w2v = wp[i + 2];
        a2 += x2.x * w2v.x + x2.y * w2v.y + x2.z * w2v.z + x2.w * w2v.w;
        float4 x3 = hp[i + 3], w3 = wp[i + 3];
        a3 += x3.x * w3.x + x3.y * w3.y + x3.z * w3.z + x3.w * w3.w;
    }
    hb[gid] = attn_b[h] + ((a0 + a1) + (a2 + a3));
}

// GEMM: 128(M) x 256(N=h) tile per block. 4 waves (2M x 2N), wave tile 64x128.
// BK=32, double-buffered LDS, global_load_lds staging, 2 blocks/CU.
// A fp32 in LDS, converted bf16 on read. Epilogue reduces 256 h -> part[nt].
__global__ __launch_bounds__(256, 2) void gemm_kernel(
    const float* __restrict__ enc,      // [65536][512] f32 (row = s*64+b)
    const ushort_t* __restrict__ w2,    // [512][512] bf16
    const float* __restrict__ hb,       // [64][512] f32
    const float* __restrict__ vw,       // [512] f32
    float* __restrict__ part)           // [2][65536] f32
{
    __shared__ __align__(16) float As[2][128 * 32];      // 16 KB x2 fp32
    __shared__ __align__(16) ushort_t Bs[2][256 * 32];   // 16 KB x2 bf16
    __shared__ float red[2][128];

    const int tid = threadIdx.x;
    const int bid = blockIdx.x;
    // pair-swizzle: both nt of an mt on the same XCD, adjacent in dispatch
    const int xcd = bid & 7, j = bid >> 3;
    const int mt = xcd * 64 + (j >> 1), nt = j & 1;
    const size_t m0 = (size_t)mt * 128;
    const int h0 = nt * 256;

    const int wv = tid >> 6, l = tid & 63;
    const int wm = wv >> 1, wn = wv & 1;
    const int lr = l & 15, lq = l >> 4;

    // ---- A staging: 4 gload_lds/thread. 16B-unit u = i*256 + wv*64 + l
    // row = u>>3, slot p = l&7, swizzled source unit j = p ^ (row&7)
    const float* aG[4];
    uint_t aL[4];
    #pragma unroll
    for (int i = 0; i < 4; i++) {
        int rowA = i * 32 + wv * 8 + (l >> 3);
        int jA = (l & 7) ^ (l >> 3);
        aG[i] = enc + (m0 + rowA) * 512 + jA * 4;
        aL[i] = (uint_t)(i * 256 + wv * 64) * 16;   // wave-uniform byte base
    }
    // ---- B staging: 4 gload_lds/thread. unit u = i*256 + wv*64 + l
    // row = u>>2, p = u&3, source unit j = p ^ ((row>>1)&3)
    const ushort_t* bG[4];
    uint_t bL[4];
    #pragma unroll
    for (int i = 0; i < 4; i++) {
        int rowB = i * 64 + wv * 16 + (l >> 2);
        int jB = (l & 3) ^ ((l >> 3) & 3);
        bG[i] = w2 + (size_t)(h0 + rowB) * 512 + jB * 8;
        bL[i] = (uint_t)(i * 256 + wv * 64) * 16;
    }

    // ---- fragment read byte-offsets (inverse of same involutions) ----
    uint_t aoffL[4], aoffH[4], boff[8];
    #pragma unroll
    for (int mf = 0; mf < 4; mf++) {
        int row = wm * 64 + mf * 16 + lr;
        aoffL[mf] = (uint_t)row * 128 + (uint_t)(((lq * 2 + 0) ^ (row & 7)) * 16);
        aoffH[mf] = (uint_t)row * 128 + (uint_t)(((lq * 2 + 1) ^ (row & 7)) * 16);
    }
    #pragma unroll
    for (int nf = 0; nf < 8; nf++) {
        int r = wn * 128 + nf * 16 + lr;
        boff[nf] = (uint_t)r * 64 + (uint_t)((lq ^ ((r >> 1) & 3)) * 16);
    }

    #define STAGE(kt, buf) do { \
        _Pragma("unroll") \
        for (int i = 0; i < 4; i++) GL16(aG[i] + (kt) * 32, (char*)(&As[(buf)][0]) + aL[i]); \
        _Pragma("unroll") \
        for (int i = 0; i < 4; i++) GL16(bG[i] + (kt) * 32, (char*)(&Bs[(buf)][0]) + bL[i]); \
    } while (0)

    // prologue: stage k-tile 0
    STAGE(0, 0);
    __syncthreads();

    f32x4 acc[4][8] = {};

    #pragma unroll 2
    for (int kt = 0; kt < 16; ++kt) {
        const int cur = kt & 1;
        if (kt < 15) STAGE(kt + 1, cur ^ 1);
        short8 af[4], bfr[8];
        #pragma unroll
        for (int nf = 0; nf < 8; nf++)
            bfr[nf] = *(const short8*)((const char*)(&Bs[cur][0]) + boff[nf]);
        #pragma unroll
        for (int mf = 0; mf < 4; mf++) {
            f32x4 lo = *(const f32x4*)((const char*)(&As[cur][0]) + aoffL[mf]);
            f32x4 hi = *(const f32x4*)((const char*)(&As[cur][0]) + aoffH[mf]);
            union { short8 s; uint_t u[4]; } t;
            t.u[0] = pkbf(lo[0], lo[1]);
            t.u[1] = pkbf(lo[2], lo[3]);
            t.u[2] = pkbf(hi[0], hi[1]);
            t.u[3] = pkbf(hi[2], hi[3]);
            af[mf] = t.s;
        }
        #pragma unroll
        for (int mf = 0; mf < 4; mf++)
            #pragma unroll
            for (int nf = 0; nf < 8; nf++)
                acc[mf][nf] = __builtin_amdgcn_mfma_f32_16x16x32_bf16(af[mf], bfr[nf], acc[mf][nf], 0, 0, 0);
        __syncthreads();
    }
    #undef STAGE

    // ---- epilogue: tanh(pre + hb) * v, reduce over this block's 256 h ----
    float vv[8];
    #pragma unroll
    for (int nf = 0; nf < 8; nf++) vv[nf] = vw[h0 + wn * 128 + nf * 16 + lr];

    #pragma unroll
    for (int mf = 0; mf < 4; mf++) {
        #pragma unroll
        for (int r = 0; r < 4; r++) {
            int row = wm * 64 + mf * 16 + lq * 4 + r;   // 0..127
            int b = row & 63;
            const float* hbp = hb + b * 512 + h0 + wn * 128 + lr;
            float p = 0.f;
            #pragma unroll
            for (int nf = 0; nf < 8; nf++) {
                float x = acc[mf][nf][r] + hbp[nf * 16];
                p += tanh_fast(x) * vv[nf];
            }
            p += __shfl_xor(p, 1);
            p += __shfl_xor(p, 2);
            p += __shfl_xor(p, 4);
            p += __shfl_xor(p, 8);
            if (lr == 0) red[wn][row] = p;
        }
    }
    __syncthreads();
    if (tid < 128) {
        part[(size_t)nt * 65536 + m0 + tid] = red[0][tid] + red[1][tid];
    }
}

// Masked softmax over s for each b. part layout [2][s*64+b], out [b][s].
__global__ void softmax_kernel(const float* __restrict__ part,
                               const int* __restrict__ mask,
                               float* __restrict__ out) {
    __shared__ float sred[8];
    int b = blockIdx.x;
    int t = threadIdx.x;  // 256
    float vals[4];
    float mx = -INFINITY;
    #pragma unroll
    for (int i = 0; i < 4; i++) {
        int s = t + i * 256;
        int row = s * 64 + b;
        float x = part[row] + part[65536 + row];
        if (mask[b * 1024 + s] == 0) x = NEG_VAL;
        vals[i] = x;
        mx = fmaxf(mx, x);
    }
    #pragma unroll
    for (int o = 32; o; o >>= 1) mx = fmaxf(mx, __shfl_xor(mx, o));
    int w = t >> 6;
    if ((t & 63) == 0) sred[w] = mx;
    __syncthreads();
    mx = fmaxf(fmaxf(sred[0], sred[1]), fmaxf(sred[2], sred[3]));
    float sum = 0.f;
    #pragma unroll
    for (int i = 0; i < 4; i++) {
        vals[i] = __expf(vals[i] - mx);
        sum += vals[i];
    }
    #pragma unroll
    for (int o = 32; o; o >>= 1) sum += __shfl_xor(sum, o);
    if ((t & 63) == 0) sred[4 + w] = sum;
    __syncthreads();
    float tot = (sred[4] + sred[5]) + (sred[6] + sred[7]);
    float inv = 1.0f / tot;
    #pragma unroll
    for (int i = 0; i < 4; i++) out[b * 1024 + t + i * 256] = vals[i] * inv;
}

extern "C" void kernel_launch(void* const* d_in, const int* in_sizes, int n_in,
                              void* d_out, int out_size, void* d_ws, size_t ws_size,
                              hipStream_t stream) {
    const float* hidden = (const float*)d_in[1];
    const float* enc    = (const float*)d_in[2];
    const int*   mask   = (const int*)d_in[3];
    const float* attn_w = (const float*)d_in[9];
    const float* attn_b = (const float*)d_in[10];
    const float* vw     = (const float*)d_in[11];
    float* out = (float*)d_out;

    char* ws = (char*)d_ws;
    ushort_t* w2 = (ushort_t*)ws;                    // 512 KB
    float* hb   = (float*)(ws + 512 * 1024);         // 128 KB
    float* part = (float*)(ws + 640 * 1024);         // 512 KB (2 x 65536 f32)

    w2conv_kernel<<<256, 256, 0, stream>>>(attn_w, w2);
    hproj_kernel<<<128, 256, 0, stream>>>(hidden, attn_w, attn_b, hb);
    gemm_kernel<<<1024, 256, 0, stream>>>(enc, w2, hb, vw, part);
    softmax_kernel<<<64, 256, 0, stream>>>(part, mask, out);
}

// Round 7
// 95.513 us; speedup vs baseline: 2.3989x; 1.0473x over previous
//
#include <hip/hip_runtime.h>
#include <hip/hip_bf16.h>

typedef unsigned short ushort_t;
typedef unsigned int uint_t;
typedef __attribute__((ext_vector_type(8))) short short8;
typedef __attribute__((ext_vector_type(4))) float f32x4;

#define NEG_VAL -1e10f

#define GL16(gp, lp) __builtin_amdgcn_global_load_lds( \
    (const __attribute__((address_space(1))) uint_t*)(gp), \
    (__attribute__((address_space(3))) uint_t*)(lp), 16, 0, 0)

__device__ __forceinline__ ushort_t f2bf(float x) {
    uint_t u = __float_as_uint(x);
    uint_t r = (u + 0x7fffu + ((u >> 16) & 1u)) >> 16;
    return (ushort_t)r;
}

__device__ __forceinline__ uint_t pkbf(float a, float b) {
    return (uint_t)f2bf(a) | ((uint_t)f2bf(b) << 16);
}

// single-instruction packed fp32x2 -> bf16x2 (RNE), dst.lo = a, dst.hi = b
__device__ __forceinline__ uint_t cvtpk(float a, float b) {
    uint_t r;
    asm("v_cvt_pk_bf16_f32 %0, %1, %2" : "=v"(r) : "v"(a), "v"(b));
    return r;
}

__device__ __forceinline__ float tanh_fast(float x) {
    float e = __expf(2.0f * x);
    return 1.0f - 2.0f / (e + 1.0f);
}

// attn_w[:, 512:1024] (f32 [512][1024]) -> w2 bf16 [512][512]
__global__ void w2conv_kernel(const float* __restrict__ attn_w, ushort_t* __restrict__ w2) {
    int gid = blockIdx.x * 256 + threadIdx.x;  // 65536 quads
    int h = gid >> 7, q = gid & 127;
    float4 v = *(const float4*)(attn_w + (size_t)h * 1024 + 512 + q * 4);
    uint2 p;
    p.x = pkbf(v.x, v.y);
    p.y = pkbf(v.z, v.w);
    *(uint2*)(w2 + h * 512 + q * 4) = p;
}

// hb[b][h] = attn_b[h] + sum_k hidden[b,k] * attn_w[h,k]   (fp32 exact)
__global__ void hproj_kernel(const float* __restrict__ hidden,
                             const float* __restrict__ attn_w,
                             const float* __restrict__ attn_b,
                             float* __restrict__ hb) {
    int gid = blockIdx.x * 256 + threadIdx.x;  // 32768
    int b = gid >> 9, h = gid & 511;
    const float4* hp = (const float4*)(hidden + (size_t)b * 512);
    const float4* wp = (const float4*)(attn_w + (size_t)h * 1024);
    float a0 = 0.f, a1 = 0.f, a2 = 0.f, a3 = 0.f;
    #pragma unroll 4
    for (int i = 0; i < 128; i += 4) {
        float4 x0 = hp[i + 0], w0 = wp[i + 0];
        a0 += x0.x * w0.x + x0.y * w0.y + x0.z * w0.z + x0.w * w0.w;
        float4 x1 = hp[i + 1], w1 = wp[i + 1];
        a1 += x1.x * w1.x + x1.y * w1.y + x1.z * w1.z + x1.w * w1.w;
        float4 x2 = hp[i + 2], w2v = wp[i + 2];
        a2 += x2.x * w2v.x + x2.y * w2v.y + x2.z * w2v.z + x2.w * w2v.w;
        float4 x3 = hp[i + 3], w3 = wp[i + 3];
        a3 += x3.x * w3.x + x3.y * w3.y + x3.z * w3.z + x3.w * w3.w;
    }
    hb[gid] = attn_b[h] + ((a0 + a1) + (a2 + a3));
}

// GEMM: 128(M) x 256(N=h) tile per block. 4 waves (2M x 2N), wave tile 64x128.
// BK=32, double-buffered LDS, global_load_lds staging, 2 blocks/CU.
// A fp32 in LDS, converted bf16 on read via v_cvt_pk_bf16_f32.
__global__ __launch_bounds__(256, 2) void gemm_kernel(
    const float* __restrict__ enc,      // [65536][512] f32 (row = s*64+b)
    const ushort_t* __restrict__ w2,    // [512][512] bf16
    const float* __restrict__ hb,       // [64][512] f32
    const float* __restrict__ vw,       // [512] f32
    float* __restrict__ part)           // [2][65536] f32
{
    __shared__ __align__(16) float As[2][128 * 32];      // 16 KB x2 fp32
    __shared__ __align__(16) ushort_t Bs[2][256 * 32];   // 16 KB x2 bf16
    __shared__ float red[2][128];

    const int tid = threadIdx.x;
    const int bid = blockIdx.x;
    // pair-swizzle: both nt of an mt on the same XCD, adjacent in dispatch
    const int xcd = bid & 7, j = bid >> 3;
    const int mt = xcd * 64 + (j >> 1), nt = j & 1;
    const size_t m0 = (size_t)mt * 128;
    const int h0 = nt * 256;

    const int wv = tid >> 6, l = tid & 63;
    const int wm = wv >> 1, wn = wv & 1;
    const int lr = l & 15, lq = l >> 4;

    // ---- A staging: 4 gload_lds/thread. 16B-unit u = i*256 + wv*64 + l
    // row = u>>3, slot p = l&7, swizzled source unit j = p ^ (row&7)
    const float* aG[4];
    uint_t aL[4];
    #pragma unroll
    for (int i = 0; i < 4; i++) {
        int rowA = i * 32 + wv * 8 + (l >> 3);
        int jA = (l & 7) ^ (l >> 3);
        aG[i] = enc + (m0 + rowA) * 512 + jA * 4;
        aL[i] = (uint_t)(i * 256 + wv * 64) * 16;   // wave-uniform byte base
    }
    // ---- B staging: 4 gload_lds/thread. unit u = i*256 + wv*64 + l
    // row = u>>2, p = u&3, source unit j = p ^ ((row>>1)&3)
    const ushort_t* bG[4];
    uint_t bL[4];
    #pragma unroll
    for (int i = 0; i < 4; i++) {
        int rowB = i * 64 + wv * 16 + (l >> 2);
        int jB = (l & 3) ^ ((l >> 3) & 3);
        bG[i] = w2 + (size_t)(h0 + rowB) * 512 + jB * 8;
        bL[i] = (uint_t)(i * 256 + wv * 64) * 16;
    }

    // ---- fragment read byte-offsets (inverse of same involutions) ----
    uint_t aoffL[4], aoffH[4], boff[8];
    #pragma unroll
    for (int mf = 0; mf < 4; mf++) {
        int row = wm * 64 + mf * 16 + lr;
        aoffL[mf] = (uint_t)row * 128 + (uint_t)(((lq * 2 + 0) ^ (row & 7)) * 16);
        aoffH[mf] = (uint_t)row * 128 + (uint_t)(((lq * 2 + 1) ^ (row & 7)) * 16);
    }
    #pragma unroll
    for (int nf = 0; nf < 8; nf++) {
        int r = wn * 128 + nf * 16 + lr;
        boff[nf] = (uint_t)r * 64 + (uint_t)((lq ^ ((r >> 1) & 3)) * 16);
    }

    #define STAGE(kt, buf) do { \
        _Pragma("unroll") \
        for (int i = 0; i < 4; i++) GL16(aG[i] + (kt) * 32, (char*)(&As[(buf)][0]) + aL[i]); \
        _Pragma("unroll") \
        for (int i = 0; i < 4; i++) GL16(bG[i] + (kt) * 32, (char*)(&Bs[(buf)][0]) + bL[i]); \
    } while (0)

    // prologue: stage k-tile 0
    STAGE(0, 0);
    __syncthreads();

    f32x4 acc[4][8] = {};

    #pragma unroll 2
    for (int kt = 0; kt < 16; ++kt) {
        const int cur = kt & 1;
        if (kt < 15) STAGE(kt + 1, cur ^ 1);
        short8 af[4], bfr[8];
        #pragma unroll
        for (int nf = 0; nf < 8; nf++)
            bfr[nf] = *(const short8*)((const char*)(&Bs[cur][0]) + boff[nf]);
        #pragma unroll
        for (int mf = 0; mf < 4; mf++) {
            f32x4 lo = *(const f32x4*)((const char*)(&As[cur][0]) + aoffL[mf]);
            f32x4 hi = *(const f32x4*)((const char*)(&As[cur][0]) + aoffH[mf]);
            union { short8 s; uint_t u[4]; } t;
            t.u[0] = cvtpk(lo[0], lo[1]);
            t.u[1] = cvtpk(lo[2], lo[3]);
            t.u[2] = cvtpk(hi[0], hi[1]);
            t.u[3] = cvtpk(hi[2], hi[3]);
            af[mf] = t.s;
        }
        #pragma unroll
        for (int mf = 0; mf < 4; mf++)
            #pragma unroll
            for (int nf = 0; nf < 8; nf++)
                acc[mf][nf] = __builtin_amdgcn_mfma_f32_16x16x32_bf16(af[mf], bfr[nf], acc[mf][nf], 0, 0, 0);
        __syncthreads();
    }
    #undef STAGE

    // ---- epilogue: tanh(pre + hb) * v, reduce over this block's 256 h ----
    float vv[8];
    #pragma unroll
    for (int nf = 0; nf < 8; nf++) vv[nf] = vw[h0 + wn * 128 + nf * 16 + lr];

    #pragma unroll
    for (int mf = 0; mf < 4; mf++) {
        #pragma unroll
        for (int r = 0; r < 4; r++) {
            int row = wm * 64 + mf * 16 + lq * 4 + r;   // 0..127
            int b = row & 63;
            const float* hbp = hb + b * 512 + h0 + wn * 128 + lr;
            float p = 0.f;
            #pragma unroll
            for (int nf = 0; nf < 8; nf++) {
                float x = acc[mf][nf][r] + hbp[nf * 16];
                p += tanh_fast(x) * vv[nf];
            }
            p += __shfl_xor(p, 1);
            p += __shfl_xor(p, 2);
            p += __shfl_xor(p, 4);
            p += __shfl_xor(p, 8);
            if (lr == 0) red[wn][row] = p;
        }
    }
    __syncthreads();
    if (tid < 128) {
        part[(size_t)nt * 65536 + m0 + tid] = red[0][tid] + red[1][tid];
    }
}

// Masked softmax over s for each b. part layout [2][s*64+b], out [b][s].
__global__ void softmax_kernel(const float* __restrict__ part,
                               const int* __restrict__ mask,
                               float* __restrict__ out) {
    __shared__ float sred[8];
    int b = blockIdx.x;
    int t = threadIdx.x;  // 256
    float vals[4];
    float mx = -INFINITY;
    #pragma unroll
    for (int i = 0; i < 4; i++) {
        int s = t + i * 256;
        int row = s * 64 + b;
        float x = part[row] + part[65536 + row];
        if (mask[b * 1024 + s] == 0) x = NEG_VAL;
        vals[i] = x;
        mx = fmaxf(mx, x);
    }
    #pragma unroll
    for (int o = 32; o; o >>= 1) mx = fmaxf(mx, __shfl_xor(mx, o));
    int w = t >> 6;
    if ((t & 63) == 0) sred[w] = mx;
    __syncthreads();
    mx = fmaxf(fmaxf(sred[0], sred[1]), fmaxf(sred[2], sred[3]));
    float sum = 0.f;
    #pragma unroll
    for (int i = 0; i < 4; i++) {
        vals[i] = __expf(vals[i] - mx);
        sum += vals[i];
    }
    #pragma unroll
    for (int o = 32; o; o >>= 1) sum += __shfl_xor(sum, o);
    if ((t & 63) == 0) sred[4 + w] = sum;
    __syncthreads();
    float tot = (sred[4] + sred[5]) + (sred[6] + sred[7]);
    float inv = 1.0f / tot;
    #pragma unroll
    for (int i = 0; i < 4; i++) out[b * 1024 + t + i * 256] = vals[i] * inv;
}

extern "C" void kernel_launch(void* const* d_in, const int* in_sizes, int n_in,
                              void* d_out, int out_size, void* d_ws, size_t ws_size,
                              hipStream_t stream) {
    const float* hidden = (const float*)d_in[1];
    const float* enc    = (const float*)d_in[2];
    const int*   mask   = (const int*)d_in[3];
    const float* attn_w = (const float*)d_in[9];
    const float* attn_b = (const float*)d_in[10];
    const float* vw     = (const float*)d_in[11];
    float* out = (float*)d_out;

    char* ws = (char*)d_ws;
    ushort_t* w2 = (ushort_t*)ws;                    // 512 KB
    float* hb   = (float*)(ws + 512 * 1024);         // 128 KB
    float* part = (float*)(ws + 640 * 1024);         // 512 KB (2 x 65536 f32)

    w2conv_kernel<<<256, 256, 0, stream>>>(attn_w, w2);
    hproj_kernel<<<128, 256, 0, stream>>>(hidden, attn_w, attn_b, hb);
    gemm_kernel<<<1024, 256, 0, stream>>>(enc, w2, hb, vw, part);
    softmax_kernel<<<64, 256, 0, stream>>>(part, mask, out);
}